// Round 1
// baseline (1142.787 us; speedup 1.0000x reference)
//
#include <hip/hip_runtime.h>
#include <stdint.h>

#define LDIFF 0.24f

constexpr int H = 512, W = 512, NB = 2;
constexpr int HW = H * W;              // 262144 = 2^18
constexpr int N_D = NB * HW;           // 524288
constexpr int CVH = 511, CVW = 512;
constexpr int CHH = 512, CHW = 511;
constexpr int N_CV = NB * CVH * CVW;   // 523264
constexpr int N_CH = NB * CHH * CHW;   // 523264
constexpr int NBLKS = 11;              // 11x11 block grid, step 48

// ---------------- min reduction (orderable-uint trick) ----------------
__global__ void kmin(const float* __restrict__ x, unsigned* out) {
    __shared__ unsigned sm[256];
    unsigned m = 0xFFFFFFFFu;
    for (int p = blockIdx.x * blockDim.x + threadIdx.x; p < N_D; p += gridDim.x * blockDim.x) {
        unsigned u = __float_as_uint(x[p]);
        u = (u & 0x80000000u) ? ~u : (u | 0x80000000u);
        m = min(m, u);
    }
    sm[threadIdx.x] = m;
    __syncthreads();
    for (int s = 128; s; s >>= 1) {
        if (threadIdx.x < s) sm[threadIdx.x] = min(sm[threadIdx.x], sm[threadIdx.x + s]);
        __syncthreads();
    }
    if (threadIdx.x == 0) atomicMin(out, sm[0]);
}

__device__ inline float get_shift(const unsigned* mu) {
    unsigned mdeps = __float_as_uint(0.1f) | 0x80000000u;
    return (*mu <= mdeps) ? 0.1f : 0.0f;
}

// ---------------- cv / ch (written straight into d_out) ----------------
__global__ void kcvch(const float* __restrict__ guide, float* __restrict__ cv, float* __restrict__ ch) {
    int idx = blockIdx.x * 256 + threadIdx.x;   // < 524288
    int b = idx >> 18;
    int yx = idx & (HW - 1);
    int y = yx >> 9, x = yx & 511;
    const float* g = guide + (size_t)b * 3 * HW + yx;
    const float kinv = 1.0f / (0.03f * 0.03f);
    if (y < 511) {
        float d = (fabsf(g[512] - g[0]) + fabsf(g[HW + 512] - g[HW]) + fabsf(g[2 * HW + 512] - g[2 * HW])) * (1.0f / 3.0f);
        cv[b * CVH * CVW + y * CVW + x] = 1.0f / (1.0f + d * d * kinv);
    }
    if (x < 511) {
        float d = (fabsf(g[1] - g[0]) + fabsf(g[HW + 1] - g[HW]) + fabsf(g[2 * HW + 1] - g[2 * HW])) * (1.0f / 3.0f);
        ch[b * CHH * CHW + y * CHW + x] = 1.0f / (1.0f + d * d * kinv);
    }
}

// ---------------- depth = initial + shift ----------------
__global__ void kinit(const float* __restrict__ initial, const unsigned* __restrict__ mu, float* __restrict__ D) {
    int p = blockIdx.x * 256 + threadIdx.x;
    float shift = get_shift(mu);
    if (p < N_D) D[p] = initial[p] + shift;
}

// ---------------- uniform map (3x3 box variance, zero-pad, /9) ----------------
__global__ void kuni(const float* __restrict__ cv, const float* __restrict__ ch, float* __restrict__ uni) {
    int p = blockIdx.x * 256 + threadIdx.x;
    int b = blockIdx.y;
    if (p >= 511 * 511) return;
    int y = p / 511, x = p - 511 * y;
    const float* cvb = cv + b * CVH * CVW;
    const float* chb = ch + b * CHH * CHW;
    float s1 = 0.f, s2 = 0.f;
    for (int dy = -1; dy <= 1; dy++) {
        int yy = y + dy;
        if (yy < 0 || yy >= 511) continue;
        for (int dx = -1; dx <= 1; dx++) {
            int xx = x + dx;
            if (xx < 0 || xx >= 512) continue;
            float v = cvb[yy * 512 + xx];
            s1 += v; s2 += v * v;
        }
    }
    float m1 = s1 * (1.0f / 9.0f);
    float vcv = s2 * (1.0f / 9.0f) - m1 * m1;
    s1 = 0.f; s2 = 0.f;
    for (int dy = -1; dy <= 1; dy++) {
        int yy = y + dy;
        if (yy < 0 || yy >= 512) continue;
        for (int dx = -1; dx <= 1; dx++) {
            int xx = x + dx;
            if (xx < 0 || xx >= 511) continue;
            float v = chb[yy * 511 + xx];
            s1 += v; s2 += v * v;
        }
    }
    m1 = s1 * (1.0f / 9.0f);
    float vch = s2 * (1.0f / 9.0f) - m1 * m1;
    uni[b * 511 * 511 + p] = (vcv < 0.1f && vch < 0.1f) ? 1.0f : 0.0f;
}

// ---------------- per-block params: cv_mean, ch_mean, cond ----------------
__global__ void kparams(const float* __restrict__ cv, const float* __restrict__ ch,
                        const float* __restrict__ uni, float* __restrict__ prm) {
    __shared__ float sm[256];
    int i = blockIdx.x / NBLKS, j = blockIdx.x % NBLKS, b = blockIdx.y;
    int tid = threadIdx.x;
    int y0 = i * 48, x0 = j * 48;
    int y1 = min(y0 + 64, 512), x1 = min(x0 + 64, 512);
    int bh = y1 - y0, bw = x1 - x0;
    float* out = prm + (b * 121 + blockIdx.x) * 3;

    // cv mean: rows [y0, y1-1), cols [x0, x1)
    {
        int rows = bh - 1, cols = bw, n = rows * cols;
        float s = 0.f;
        const float* p0 = cv + b * CVH * CVW + y0 * CVW + x0;
        for (int p = tid; p < n; p += 256) { int r = p / cols, c = p - r * cols; s += p0[r * CVW + c]; }
        sm[tid] = s; __syncthreads();
        for (int st = 128; st; st >>= 1) { if (tid < st) sm[tid] += sm[tid + st]; __syncthreads(); }
        if (tid == 0) out[0] = sm[0] / (float)n;
        __syncthreads();
    }
    // ch mean: rows [y0, y1), cols [x0, x1-1)
    {
        int rows = bh, cols = bw - 1, n = rows * cols;
        float s = 0.f;
        const float* p0 = ch + b * CHH * CHW + y0 * CHW + x0;
        for (int p = tid; p < n; p += 256) { int r = p / cols, c = p - r * cols; s += p0[r * CHW + c]; }
        sm[tid] = s; __syncthreads();
        for (int st = 128; st; st >>= 1) { if (tid < st) sm[tid] += sm[tid + st]; __syncthreads(); }
        if (tid == 0) out[1] = sm[0] / (float)n;
        __syncthreads();
    }
    // uniform mean -> cond
    {
        int rows = min(y1, 511) - y0, cols = min(x1, 511) - x0, n = rows * cols;
        float s = 0.f;
        const float* p0 = uni + b * 511 * 511 + y0 * 511 + x0;
        for (int p = tid; p < n; p += 256) { int r = p / cols, c = p - r * cols; s += p0[r * 511 + c]; }
        sm[tid] = s; __syncthreads();
        for (int st = 128; st; st >>= 1) { if (tid < st) sm[tid] += sm[tid + st]; __syncthreads(); }
        if (tid == 0) out[2] = (sm[0] / (float)n > 0.7f) ? 1.0f : 0.0f;
    }
}

// ---------------- per-block periodic stencil (== rfft2 * op^10 * irfft2) + blend ----------------
__global__ void kblock(float* __restrict__ depth, const float* __restrict__ prm, int t, int i_lo) {
    __shared__ float A[4096];
    __shared__ float Bs[4096];
    int i = i_lo + (int)blockIdx.x;
    int j = t - 2 * i;
    int b = blockIdx.y;
    const float* p3 = prm + (b * 121 + i * NBLKS + j) * 3;
    if (p3[2] <= 0.f) return;   // cond false: region unchanged
    float a = LDIFF * p3[0], bc = LDIFF * p3[1];
    int y0 = i * 48, x0 = j * 48;
    int y1 = min(y0 + 64, 512), x1 = min(x0 + 64, 512);
    int bh = y1 - y0, bw = x1 - x0;
    int lw = (bw == 64) ? 6 : 5;
    int mw = bw - 1, mh = bh - 1;
    int n = bh * bw;
    float* base = depth + b * HW;
    for (int p = threadIdx.x; p < n; p += 256) {
        int r = p >> lw, c = p & mw;
        A[p] = base[(y0 + r) * W + x0 + c];
    }
    __syncthreads();
    float* src = A; float* dst = Bs;
    for (int s = 0; s < 10; s++) {
        for (int p = threadIdx.x; p < n; p += 256) {
            int r = p >> lw, c = p & mw;
            float u = src[p];
            float up = src[(((r - 1) & mh) << lw) + c];
            float dn = src[(((r + 1) & mh) << lw) + c];
            float lf = src[(r << lw) + ((c - 1) & mw)];
            float rt = src[(r << lw) + ((c + 1) & mw)];
            dst[p] = u + a * (up + dn - 2.0f * u) + bc * (lf + rt - 2.0f * u);
        }
        __syncthreads();
        float* tmp = src; src = dst; dst = tmp;
    }
    for (int p = threadIdx.x; p < n; p += 256) {
        int r = p >> lw, c = p & mw;
        float by = (y0 > 0 && r < 16) ? (float)r * (1.0f / 16.0f) : 1.0f;
        float bx = (x0 > 0 && c < 16) ? (float)c * (1.0f / 16.0f) : 1.0f;
        float wgt = by * bx;
        int g = (y0 + r) * W + x0 + c;
        float orig = base[g];
        base[g] = orig * (1.0f - wgt) + src[p] * wgt;
    }
}

// ---------------- fused vertical+horizontal diffusion step ----------------
__device__ inline float vstep(const float* __restrict__ Ib, const float* __restrict__ cvb, int y, int x) {
    float u = Ib[y * 512 + x];
    float acc = u;
    if (y < 511) acc += LDIFF * cvb[y * 512 + x] * (Ib[(y + 1) * 512 + x] - u);
    if (y > 0)   acc -= LDIFF * cvb[(y - 1) * 512 + x] * (u - Ib[(y - 1) * 512 + x]);
    return acc;
}

__global__ void kstep(const float* __restrict__ I, const float* __restrict__ cv,
                      const float* __restrict__ ch, float* __restrict__ O) {
    int idx = blockIdx.x * 256 + threadIdx.x;   // < 524288
    int b = idx >> 18;
    int yx = idx & (HW - 1);
    int y = yx >> 9, x = yx & 511;
    const float* Ib = I + (b << 18);
    const float* cvb = cv + b * CVH * CVW;
    const float* chb = ch + b * CHH * CHW;
    float ip0 = vstep(Ib, cvb, y, x);
    float acc = ip0;
    if (x < 511) {
        float ipp = vstep(Ib, cvb, y, x + 1);
        acc += LDIFF * chb[y * CHW + x] * (ipp - ip0);
    }
    if (x > 0) {
        float ipm = vstep(Ib, cvb, y, x - 1);
        acc -= LDIFF * chb[y * CHW + x - 1] * (ip0 - ipm);
    }
    O[idx] = acc;
}

// ---------------- y_pred = depth - shift ----------------
__global__ void kfinal(const float* __restrict__ D, const unsigned* __restrict__ mu, float* __restrict__ yp) {
    int p = blockIdx.x * 256 + threadIdx.x;
    float shift = get_shift(mu);
    if (p < N_D) yp[p] = D[p] - shift;
}

extern "C" void kernel_launch(void* const* d_in, const int* in_sizes, int n_in,
                              void* d_out, int out_size, void* d_ws, size_t ws_size,
                              hipStream_t stream) {
    const float* guide   = (const float*)d_in[0];
    const float* initial = (const float*)d_in[1];
    float* y_pred = (float*)d_out;
    float* cv = y_pred + N_D;          // output 1
    float* ch = cv + N_CV;             // output 2

    uint8_t* w = (uint8_t*)d_ws;
    unsigned* wmin = (unsigned*)w;                       // 4 B
    float* D   = (float*)(w + 256);                      // 2 MB depth
    float* T   = (float*)(w + 256 + (size_t)N_D * 4);    // 2 MB temp (also holds uniform map early)
    float* prm = (float*)(w + 256 + (size_t)2 * N_D * 4);// 242*3 floats

    hipMemsetAsync(wmin, 0xFF, 4, stream);
    kmin<<<256, 256, 0, stream>>>(initial, wmin);
    kcvch<<<N_D / 256, 256, 0, stream>>>(guide, cv, ch);
    kinit<<<N_D / 256, 256, 0, stream>>>(initial, wmin, D);
    kuni<<<dim3((511 * 511 + 255) / 256, 2), 256, 0, stream>>>(cv, ch, T);
    kparams<<<dim3(121, 2), 256, 0, stream>>>(cv, ch, T, prm);

    // wavefront over block diagonals t = 2i + j, i,j in [0,11)
    for (int t = 0; t <= 30; t++) {
        int i_lo = (t - 10) > 0 ? (t - 9) / 2 : 0;
        int i_hi = (t / 2 < 10) ? t / 2 : 10;
        int cnt = i_hi - i_lo + 1;
        kblock<<<dim3(cnt, 2), 256, 0, stream>>>(D, prm, t, i_lo);
    }

    // 64 fused diffusion iterations, ping-pong D <-> T (ends in D)
    float* in = D; float* out = T;
    for (int it = 0; it < 64; it++) {
        kstep<<<N_D / 256, 256, 0, stream>>>(in, cv, ch, out);
        float* tmp = in; in = out; out = tmp;
    }

    kfinal<<<N_D / 256, 256, 0, stream>>>(D, wmin, y_pred);
}

// Round 2
// 913.969 us; speedup vs baseline: 1.2504x; 1.2504x over previous
//
#include <hip/hip_runtime.h>
#include <stdint.h>

#define LDIFF 0.24f

constexpr int H = 512, W = 512, NB = 2;
constexpr int HW = H * W;              // 262144 = 2^18
constexpr int N_D = NB * HW;           // 524288
constexpr int CVH = 511, CVW = 512;
constexpr int CHH = 512, CHW = 511;
constexpr int N_CV = NB * CVH * CVW;   // 523264
constexpr int N_CH = NB * CHH * CHW;   // 523264
constexpr int NBLKS = 11;              // 11x11 block grid, step 48

// ---------------- min reduction (orderable-uint trick) ----------------
__global__ void kmin(const float* __restrict__ x, unsigned* out) {
    __shared__ unsigned sm[256];
    unsigned m = 0xFFFFFFFFu;
    for (int p = blockIdx.x * blockDim.x + threadIdx.x; p < N_D; p += gridDim.x * blockDim.x) {
        unsigned u = __float_as_uint(x[p]);
        u = (u & 0x80000000u) ? ~u : (u | 0x80000000u);
        m = min(m, u);
    }
    sm[threadIdx.x] = m;
    __syncthreads();
    for (int s = 128; s; s >>= 1) {
        if (threadIdx.x < s) sm[threadIdx.x] = min(sm[threadIdx.x], sm[threadIdx.x + s]);
        __syncthreads();
    }
    if (threadIdx.x == 0) atomicMin(out, sm[0]);
}

__device__ inline float get_shift(const unsigned* mu) {
    unsigned mdeps = __float_as_uint(0.1f) | 0x80000000u;
    return (*mu <= mdeps) ? 0.1f : 0.0f;
}

// ---------------- cv / ch (written straight into d_out) ----------------
__global__ void kcvch(const float* __restrict__ guide, float* __restrict__ cv, float* __restrict__ ch) {
    int idx = blockIdx.x * 256 + threadIdx.x;   // < 524288
    int b = idx >> 18;
    int yx = idx & (HW - 1);
    int y = yx >> 9, x = yx & 511;
    const float* g = guide + (size_t)b * 3 * HW + yx;
    const float kinv = 1.0f / (0.03f * 0.03f);
    if (y < 511) {
        float d = (fabsf(g[512] - g[0]) + fabsf(g[HW + 512] - g[HW]) + fabsf(g[2 * HW + 512] - g[2 * HW])) * (1.0f / 3.0f);
        cv[b * CVH * CVW + y * CVW + x] = 1.0f / (1.0f + d * d * kinv);
    }
    if (x < 511) {
        float d = (fabsf(g[1] - g[0]) + fabsf(g[HW + 1] - g[HW]) + fabsf(g[2 * HW + 1] - g[2 * HW])) * (1.0f / 3.0f);
        ch[b * CHH * CHW + y * CHW + x] = 1.0f / (1.0f + d * d * kinv);
    }
}

// ---------------- depth = initial + shift ----------------
__global__ void kinit(const float* __restrict__ initial, const unsigned* __restrict__ mu, float* __restrict__ D) {
    int p = blockIdx.x * 256 + threadIdx.x;
    float shift = get_shift(mu);
    if (p < N_D) D[p] = initial[p] + shift;
}

// ---------------- uniform map (3x3 box variance, zero-pad, /9) ----------------
__global__ void kuni(const float* __restrict__ cv, const float* __restrict__ ch, float* __restrict__ uni) {
    int p = blockIdx.x * 256 + threadIdx.x;
    int b = blockIdx.y;
    if (p >= 511 * 511) return;
    int y = p / 511, x = p - 511 * y;
    const float* cvb = cv + b * CVH * CVW;
    const float* chb = ch + b * CHH * CHW;
    float s1 = 0.f, s2 = 0.f;
    for (int dy = -1; dy <= 1; dy++) {
        int yy = y + dy;
        if (yy < 0 || yy >= 511) continue;
        for (int dx = -1; dx <= 1; dx++) {
            int xx = x + dx;
            if (xx < 0 || xx >= 512) continue;
            float v = cvb[yy * 512 + xx];
            s1 += v; s2 += v * v;
        }
    }
    float m1 = s1 * (1.0f / 9.0f);
    float vcv = s2 * (1.0f / 9.0f) - m1 * m1;
    s1 = 0.f; s2 = 0.f;
    for (int dy = -1; dy <= 1; dy++) {
        int yy = y + dy;
        if (yy < 0 || yy >= 512) continue;
        for (int dx = -1; dx <= 1; dx++) {
            int xx = x + dx;
            if (xx < 0 || xx >= 511) continue;
            float v = chb[yy * 511 + xx];
            s1 += v; s2 += v * v;
        }
    }
    m1 = s1 * (1.0f / 9.0f);
    float vch = s2 * (1.0f / 9.0f) - m1 * m1;
    uni[b * 511 * 511 + p] = (vcv < 0.1f && vch < 0.1f) ? 1.0f : 0.0f;
}

// ---------------- per-block params: cv_mean, ch_mean, cond ----------------
__global__ void kparams(const float* __restrict__ cv, const float* __restrict__ ch,
                        const float* __restrict__ uni, float* __restrict__ prm) {
    __shared__ float sm[256];
    int i = blockIdx.x / NBLKS, j = blockIdx.x % NBLKS, b = blockIdx.y;
    int tid = threadIdx.x;
    int y0 = i * 48, x0 = j * 48;
    int y1 = min(y0 + 64, 512), x1 = min(x0 + 64, 512);
    int bh = y1 - y0, bw = x1 - x0;
    float* out = prm + (b * 121 + blockIdx.x) * 3;

    // cv mean: rows [y0, y1-1), cols [x0, x1)
    {
        int rows = bh - 1, cols = bw, n = rows * cols;
        float s = 0.f;
        const float* p0 = cv + b * CVH * CVW + y0 * CVW + x0;
        for (int p = tid; p < n; p += 256) { int r = p / cols, c = p - r * cols; s += p0[r * CVW + c]; }
        sm[tid] = s; __syncthreads();
        for (int st = 128; st; st >>= 1) { if (tid < st) sm[tid] += sm[tid + st]; __syncthreads(); }
        if (tid == 0) out[0] = sm[0] / (float)n;
        __syncthreads();
    }
    // ch mean: rows [y0, y1), cols [x0, x1-1)
    {
        int rows = bh, cols = bw - 1, n = rows * cols;
        float s = 0.f;
        const float* p0 = ch + b * CHH * CHW + y0 * CHW + x0;
        for (int p = tid; p < n; p += 256) { int r = p / cols, c = p - r * cols; s += p0[r * CHW + c]; }
        sm[tid] = s; __syncthreads();
        for (int st = 128; st; st >>= 1) { if (tid < st) sm[tid] += sm[tid + st]; __syncthreads(); }
        if (tid == 0) out[1] = sm[0] / (float)n;
        __syncthreads();
    }
    // uniform mean -> cond
    {
        int rows = min(y1, 511) - y0, cols = min(x1, 511) - x0, n = rows * cols;
        float s = 0.f;
        const float* p0 = uni + b * 511 * 511 + y0 * 511 + x0;
        for (int p = tid; p < n; p += 256) { int r = p / cols, c = p - r * cols; s += p0[r * 511 + c]; }
        sm[tid] = s; __syncthreads();
        for (int st = 128; st; st >>= 1) { if (tid < st) sm[tid] += sm[tid + st]; __syncthreads(); }
        if (tid == 0) out[2] = (sm[0] / (float)n > 0.7f) ? 1.0f : 0.0f;
    }
}

// ---------------- per-block periodic stencil (== rfft2 * op^10 * irfft2) + blend ----------------
__global__ void kblock(float* __restrict__ depth, const float* __restrict__ prm, int t, int i_lo) {
    __shared__ float A[4096];
    __shared__ float Bs[4096];
    int i = i_lo + (int)blockIdx.x;
    int j = t - 2 * i;
    int b = blockIdx.y;
    const float* p3 = prm + (b * 121 + i * NBLKS + j) * 3;
    if (p3[2] <= 0.f) return;   // cond false: region unchanged
    float a = LDIFF * p3[0], bc = LDIFF * p3[1];
    int y0 = i * 48, x0 = j * 48;
    int y1 = min(y0 + 64, 512), x1 = min(x0 + 64, 512);
    int bh = y1 - y0, bw = x1 - x0;
    int lw = (bw == 64) ? 6 : 5;
    int mw = bw - 1, mh = bh - 1;
    int n = bh * bw;
    float* base = depth + b * HW;
    for (int p = threadIdx.x; p < n; p += 256) {
        int r = p >> lw, c = p & mw;
        A[p] = base[(y0 + r) * W + x0 + c];
    }
    __syncthreads();
    float* src = A; float* dst = Bs;
    for (int s = 0; s < 10; s++) {
        for (int p = threadIdx.x; p < n; p += 256) {
            int r = p >> lw, c = p & mw;
            float u = src[p];
            float up = src[(((r - 1) & mh) << lw) + c];
            float dn = src[(((r + 1) & mh) << lw) + c];
            float lf = src[(r << lw) + ((c - 1) & mw)];
            float rt = src[(r << lw) + ((c + 1) & mw)];
            dst[p] = u + a * (up + dn - 2.0f * u) + bc * (lf + rt - 2.0f * u);
        }
        __syncthreads();
        float* tmp = src; src = dst; dst = tmp;
    }
    for (int p = threadIdx.x; p < n; p += 256) {
        int r = p >> lw, c = p & mw;
        float by = (y0 > 0 && r < 16) ? (float)r * (1.0f / 16.0f) : 1.0f;
        float bx = (x0 > 0 && c < 16) ? (float)c * (1.0f / 16.0f) : 1.0f;
        float wgt = by * bx;
        int g = (y0 + r) * W + x0 + c;
        float orig = base[g];
        base[g] = orig * (1.0f - wgt) + src[p] * wgt;
    }
}

// ---------------- fused 8-iteration diffusion with halo tiles ----------------
// Output tile 48x48, halo 8 each side -> 64x64 LDS working set.
// cv/ch zero-padded outside their valid ranges == boundary conditionals.
__global__ __launch_bounds__(256) void kdiff8(const float* __restrict__ I,
                                              const float* __restrict__ cv,
                                              const float* __restrict__ ch,
                                              float* __restrict__ O) {
    __shared__ float buf[4096];
    __shared__ float V[4096];
    __shared__ float cvT[4096];
    __shared__ float chT[4096];
    int bx = blockIdx.x, by = blockIdx.y, b = blockIdx.z;
    int gy0 = by * 48 - 8, gx0 = bx * 48 - 8;
    int tid = threadIdx.x;
    const float* Ib = I + b * HW;
    const float* cvb = cv + b * CVH * CVW;
    const float* chb = ch + b * CHH * CHW;

    #pragma unroll
    for (int k = 0; k < 16; k++) {
        int p = tid + k * 256;
        int r = p >> 6, c = p & 63;
        int cy = gy0 + r, cx = gx0 + c;
        int gy = min(max(cy, 0), 511), gx = min(max(cx, 0), 511);
        buf[p] = Ib[gy * W + gx];
        cvT[p] = (cy >= 0 && cy < 511 && cx >= 0 && cx < 512) ? cvb[cy * CVW + cx] : 0.0f;
        chT[p] = (cy >= 0 && cy < 512 && cx >= 0 && cx < 511) ? chb[cy * CHW + cx] : 0.0f;
    }
    __syncthreads();

    for (int it = 0; it < 8; it++) {
        // vertical pass: V = vstep(buf)
        #pragma unroll
        for (int k = 0; k < 16; k++) {
            int p = tid + k * 256;
            int r = p >> 6, c = p & 63;
            int rm = (r > 0) ? r - 1 : 0;
            int rp = (r < 63) ? r + 1 : 63;
            float u = buf[p];
            float up = buf[(rm << 6) + c];
            float dn = buf[(rp << 6) + c];
            V[p] = u + LDIFF * cvT[p] * (dn - u) - LDIFF * cvT[(rm << 6) + c] * (u - up);
        }
        __syncthreads();
        // horizontal pass: buf = hstep(V)
        #pragma unroll
        for (int k = 0; k < 16; k++) {
            int p = tid + k * 256;
            int r = p >> 6, c = p & 63;
            int cm = (c > 0) ? c - 1 : 0;
            int cp = (c < 63) ? c + 1 : 63;
            float v = V[p];
            float lf = V[(r << 6) + cm];
            float rt = V[(r << 6) + cp];
            buf[p] = v + LDIFF * chT[p] * (rt - v) - LDIFF * chT[(r << 6) + cm] * (v - lf);
        }
        __syncthreads();
    }

    // write central 48x48 (clipped to image)
    #pragma unroll
    for (int k = 0; k < 16; k++) {
        int p = tid + k * 256;
        int r = p >> 6, c = p & 63;
        if (r >= 8 && r < 56 && c >= 8 && c < 56) {
            int gy = gy0 + r, gx = gx0 + c;
            if (gy < 512 && gx < 512)
                O[b * HW + gy * W + gx] = buf[p];
        }
    }
}

// ---------------- y_pred = depth - shift ----------------
__global__ void kfinal(const float* __restrict__ D, const unsigned* __restrict__ mu, float* __restrict__ yp) {
    int p = blockIdx.x * 256 + threadIdx.x;
    float shift = get_shift(mu);
    if (p < N_D) yp[p] = D[p] - shift;
}

extern "C" void kernel_launch(void* const* d_in, const int* in_sizes, int n_in,
                              void* d_out, int out_size, void* d_ws, size_t ws_size,
                              hipStream_t stream) {
    const float* guide   = (const float*)d_in[0];
    const float* initial = (const float*)d_in[1];
    float* y_pred = (float*)d_out;
    float* cv = y_pred + N_D;          // output 1
    float* ch = cv + N_CV;             // output 2

    uint8_t* w = (uint8_t*)d_ws;
    unsigned* wmin = (unsigned*)w;                       // 4 B
    float* D   = (float*)(w + 256);                      // 2 MB depth
    float* T   = (float*)(w + 256 + (size_t)N_D * 4);    // 2 MB temp (also holds uniform map early)
    float* prm = (float*)(w + 256 + (size_t)2 * N_D * 4);// 242*3 floats

    hipMemsetAsync(wmin, 0xFF, 4, stream);
    kmin<<<256, 256, 0, stream>>>(initial, wmin);
    kcvch<<<N_D / 256, 256, 0, stream>>>(guide, cv, ch);
    kinit<<<N_D / 256, 256, 0, stream>>>(initial, wmin, D);
    kuni<<<dim3((511 * 511 + 255) / 256, 2), 256, 0, stream>>>(cv, ch, T);
    kparams<<<dim3(121, 2), 256, 0, stream>>>(cv, ch, T, prm);

    // wavefront over block diagonals t = 2i + j, i,j in [0,11)
    for (int t = 0; t <= 30; t++) {
        int i_lo = (t - 10) > 0 ? (t - 9) / 2 : 0;
        int i_hi = (t / 2 < 10) ? t / 2 : 10;
        int cnt = i_hi - i_lo + 1;
        kblock<<<dim3(cnt, 2), 256, 0, stream>>>(D, prm, t, i_lo);
    }

    // 64 diffusion iterations = 8 launches of 8 fused iterations, ping-pong D <-> T (ends in D)
    float* in = D; float* out = T;
    for (int l = 0; l < 8; l++) {
        kdiff8<<<dim3(NBLKS, NBLKS, 2), 256, 0, stream>>>(in, cv, ch, out);
        float* tmp = in; in = out; out = tmp;
    }

    kfinal<<<N_D / 256, 256, 0, stream>>>(D, wmin, y_pred);
}

// Round 3
// 773.361 us; speedup vs baseline: 1.4777x; 1.1818x over previous
//
#include <hip/hip_runtime.h>
#include <stdint.h>

#define LDIFF 0.24f

constexpr int H = 512, W = 512, NB = 2;
constexpr int HW = H * W;              // 262144 = 2^18
constexpr int N_D = NB * HW;           // 524288
constexpr int CVH = 511, CVW = 512;
constexpr int CHH = 512, CHW = 511;
constexpr int N_CV = NB * CVH * CVW;   // 523264
constexpr int NBLKS = 11;              // 11x11 block grid, step 48

// ---------------- cv / ch (written straight into d_out) + depth copy ----------------
// NOTE: shift is dropped everywhere: all downstream ops preserve additive
// constants exactly, so y_pred = F(initial+shift)-shift == F(initial).
__global__ void kcvch(const float* __restrict__ guide, const float* __restrict__ initial,
                      float* __restrict__ cv, float* __restrict__ ch, float* __restrict__ D) {
    int idx = blockIdx.x * 256 + threadIdx.x;   // < 524288
    int b = idx >> 18;
    int yx = idx & (HW - 1);
    int y = yx >> 9, x = yx & 511;
    const float* g = guide + (size_t)b * 3 * HW + yx;
    const float kinv = 1.0f / (0.03f * 0.03f);
    D[idx] = initial[idx];
    if (y < 511) {
        float d = (fabsf(g[512] - g[0]) + fabsf(g[HW + 512] - g[HW]) + fabsf(g[2 * HW + 512] - g[2 * HW])) * (1.0f / 3.0f);
        cv[b * CVH * CVW + y * CVW + x] = 1.0f / (1.0f + d * d * kinv);
    }
    if (x < 511) {
        float d = (fabsf(g[1] - g[0]) + fabsf(g[HW + 1] - g[HW]) + fabsf(g[2 * HW + 1] - g[2 * HW])) * (1.0f / 3.0f);
        ch[b * CHH * CHW + y * CHW + x] = 1.0f / (1.0f + d * d * kinv);
    }
}

// ---------------- single-launch wavefront: params + periodic stencil + blend ----------------
// Block (b,i,j). Deps: (i,j-1),(i-1,j-1),(i-1,j),(i-1,j+1) via device-scope flags.
// 242 blocks <= 256 CUs -> all co-resident, spin-wait is safe.
__global__ __launch_bounds__(256) void kwave(float* __restrict__ depth,
                                             const float* __restrict__ cv,
                                             const float* __restrict__ ch,
                                             int* __restrict__ flags) {
    __shared__ float A[4096];
    __shared__ float Bs[4096];
    __shared__ float sm[256];
    __shared__ float prmS[3];
    __shared__ float xT[4][64];
    __shared__ float xB[4][64];
    int idx = blockIdx.x;            // 0..120
    int i = idx / NBLKS, j = idx % NBLKS;
    int b = blockIdx.y;
    int tid = threadIdx.x;
    int y0 = i * 48, x0 = j * 48;
    int y1 = min(y0 + 64, 512), x1 = min(x0 + 64, 512);
    int bh = y1 - y0, bw = x1 - x0;
    const float* cvb = cv + b * CVH * CVW;
    const float* chb = ch + b * CHH * CHW;

    // ---- per-block params (concurrent across all blocks) ----
    float scv = 0.f, sch = 0.f, sun = 0.f;
    {
        int rows = bh - 1, cols = bw, n = rows * cols;
        for (int p = tid; p < n; p += 256) { int r = p / cols, c = p - r * cols; scv += cvb[(y0 + r) * CVW + x0 + c]; }
    }
    {
        int rows = bh, cols = bw - 1, n = rows * cols;
        for (int p = tid; p < n; p += 256) { int r = p / cols, c = p - r * cols; sch += chb[(y0 + r) * CHW + x0 + c]; }
    }
    int ur = min(y1, 511) - y0, uc = min(x1, 511) - x0;
    {
        int n = ur * uc;
        for (int p = tid; p < n; p += 256) {
            int r = p / uc, c = p - r * uc;
            int y = y0 + r, x = x0 + c;
            float s1 = 0.f, s2 = 0.f;
            for (int dy = -1; dy <= 1; dy++) {
                int yy = y + dy; if (yy < 0 || yy >= 511) continue;
                for (int dx = -1; dx <= 1; dx++) {
                    int xx = x + dx; if (xx < 0 || xx >= 512) continue;
                    float v = cvb[yy * 512 + xx]; s1 += v; s2 += v * v;
                }
            }
            float m = s1 * (1.0f / 9.0f);
            float vcv = s2 * (1.0f / 9.0f) - m * m;
            s1 = 0.f; s2 = 0.f;
            for (int dy = -1; dy <= 1; dy++) {
                int yy = y + dy; if (yy < 0 || yy >= 512) continue;
                for (int dx = -1; dx <= 1; dx++) {
                    int xx = x + dx; if (xx < 0 || xx >= 511) continue;
                    float v = chb[yy * 511 + xx]; s1 += v; s2 += v * v;
                }
            }
            m = s1 * (1.0f / 9.0f);
            float vch = s2 * (1.0f / 9.0f) - m * m;
            if (vcv < 0.1f && vch < 0.1f) sun += 1.f;
        }
    }
    sm[tid] = scv; __syncthreads();
    for (int s = 128; s; s >>= 1) { if (tid < s) sm[tid] += sm[tid + s]; __syncthreads(); }
    if (tid == 0) prmS[0] = sm[0] / (float)((bh - 1) * bw);
    __syncthreads();
    sm[tid] = sch; __syncthreads();
    for (int s = 128; s; s >>= 1) { if (tid < s) sm[tid] += sm[tid + s]; __syncthreads(); }
    if (tid == 0) prmS[1] = sm[0] / (float)(bh * (bw - 1));
    __syncthreads();
    sm[tid] = sun; __syncthreads();
    for (int s = 128; s; s >>= 1) { if (tid < s) sm[tid] += sm[tid + s]; __syncthreads(); }
    if (tid == 0) prmS[2] = (sm[0] / (float)(ur * uc) > 0.7f) ? 1.0f : 0.0f;
    __syncthreads();

    int me = b * 121 + idx;
    if (prmS[2] <= 0.5f) {
        // no write -> signal immediately (successors wait their own other deps)
        if (tid == 0) __hip_atomic_store(&flags[me], 1, __ATOMIC_RELEASE, __HIP_MEMORY_SCOPE_AGENT);
        return;
    }

    // ---- wait dependencies ----
    if (tid < 4) {
        int di = (tid == 0) ? i : i - 1;
        int dj = (tid == 0) ? j - 1 : j - 2 + tid;   // tid1->j-1, tid2->j, tid3->j+1
        if (di >= 0 && dj >= 0 && dj < NBLKS) {
            int d = b * 121 + di * NBLKS + dj;
            while (__hip_atomic_load(&flags[d], __ATOMIC_ACQUIRE, __HIP_MEMORY_SCOPE_AGENT) == 0)
                __builtin_amdgcn_s_sleep(4);
        }
    }
    __syncthreads();

    float a = LDIFF * prmS[0], bc = LDIFF * prmS[1];
    float* base = depth + b * HW;
    int lane = tid & 63, wv = tid >> 6, r0 = wv * 16;

    if (bh == 64 && bw == 64) {
        // ---- fast path: registers + shfl, periodic 64x64 ----
        float u[16], orig[16];
        #pragma unroll
        for (int k = 0; k < 16; k++) { orig[k] = base[(y0 + r0 + k) * W + x0 + lane]; u[k] = orig[k]; }
        for (int it = 0; it < 10; it++) {
            xT[wv][lane] = u[0];
            xB[wv][lane] = u[15];
            __syncthreads();
            float ub = xB[(wv + 3) & 3][lane];   // row r0-1 (periodic)
            float ut = xT[(wv + 1) & 3][lane];   // row r0+16 (periodic)
            float nu[16];
            #pragma unroll
            for (int k = 0; k < 16; k++) {
                float up = (k == 0) ? ub : u[k - 1];
                float dn = (k == 15) ? ut : u[k + 1];
                float lf = __shfl(u[k], (lane + 63) & 63);
                float rt = __shfl(u[k], (lane + 1) & 63);
                nu[k] = u[k] + a * (up + dn - 2.0f * u[k]) + bc * (lf + rt - 2.0f * u[k]);
            }
            #pragma unroll
            for (int k = 0; k < 16; k++) u[k] = nu[k];
            __syncthreads();
        }
        float bxw = (x0 > 0 && lane < 16) ? (float)lane * (1.0f / 16.0f) : 1.0f;
        #pragma unroll
        for (int k = 0; k < 16; k++) {
            int r = r0 + k;
            float byw = (y0 > 0 && r < 16) ? (float)r * (1.0f / 16.0f) : 1.0f;
            float wgt = byw * bxw;
            base[(y0 + r) * W + x0 + lane] = orig[k] * (1.0f - wgt) + u[k] * wgt;
        }
    } else {
        // ---- LDS fallback for 32-sized edge blocks ----
        int lw = (bw == 64) ? 6 : 5;
        int mw = bw - 1, mh = bh - 1;
        int n = bh * bw;
        for (int p = tid; p < n; p += 256) {
            int r = p >> lw, c = p & mw;
            A[p] = base[(y0 + r) * W + x0 + c];
        }
        __syncthreads();
        float* src = A; float* dst = Bs;
        for (int s = 0; s < 10; s++) {
            for (int p = tid; p < n; p += 256) {
                int r = p >> lw, c = p & mw;
                float u = src[p];
                float up = src[(((r - 1) & mh) << lw) + c];
                float dn = src[(((r + 1) & mh) << lw) + c];
                float lf = src[(r << lw) + ((c - 1) & mw)];
                float rt = src[(r << lw) + ((c + 1) & mw)];
                dst[p] = u + a * (up + dn - 2.0f * u) + bc * (lf + rt - 2.0f * u);
            }
            __syncthreads();
            float* tmp = src; src = dst; dst = tmp;
        }
        for (int p = tid; p < n; p += 256) {
            int r = p >> lw, c = p & mw;
            float by = (y0 > 0 && r < 16) ? (float)r * (1.0f / 16.0f) : 1.0f;
            float bx = (x0 > 0 && c < 16) ? (float)c * (1.0f / 16.0f) : 1.0f;
            float wgt = by * bx;
            int g = (y0 + r) * W + x0 + c;
            float orig = base[g];
            base[g] = orig * (1.0f - wgt) + src[p] * wgt;
        }
    }
    __syncthreads();
    __threadfence();
    if (tid == 0) __hip_atomic_store(&flags[me], 1, __ATOMIC_RELEASE, __HIP_MEMORY_SCOPE_AGENT);
}

// ---------------- fused 8-iteration diffusion, registers + shfl ----------------
// Tile 64x64 (output 48x48, halo 8). Wave wv owns rows [16wv,16wv+16), col = lane.
// cv/ch zero outside valid ranges == exact boundary handling.
__global__ __launch_bounds__(256) void kdiff8(const float* __restrict__ I,
                                              const float* __restrict__ cv,
                                              const float* __restrict__ ch,
                                              float* __restrict__ O) {
    __shared__ float xT[4][64];
    __shared__ float xB[4][64];
    __shared__ float cvB[4][64];
    int bx = blockIdx.x, by = blockIdx.y, b = blockIdx.z;
    int gy0 = by * 48 - 8, gx0 = bx * 48 - 8;
    int tid = threadIdx.x;
    int lane = tid & 63, wv = tid >> 6, r0 = wv * 16;
    const float* Ib = I + b * HW;
    const float* cvb = cv + b * CVH * CVW;
    const float* chb = ch + b * CHH * CHW;
    int cx = gx0 + lane;
    int gxc = min(max(cx, 0), 511);
    bool xvalid = (cx >= 0 && cx < 512);

    float u[16], cvr[16], chr[16], chl[16];
    #pragma unroll
    for (int k = 0; k < 16; k++) {
        int cy = gy0 + r0 + k;
        int gyc = min(max(cy, 0), 511);
        u[k] = Ib[gyc * W + gxc];
        cvr[k] = (cy >= 0 && cy < 511 && xvalid) ? cvb[cy * CVW + cx] : 0.0f;
        chr[k] = (cy >= 0 && cy < 512 && xvalid && cx < 511) ? chb[cy * CHW + cx] : 0.0f;
    }
    cvB[wv][lane] = cvr[15];
    #pragma unroll
    for (int k = 0; k < 16; k++) {
        float v = __shfl(chr[k], (lane + 63) & 63);
        chl[k] = (lane == 0) ? 0.0f : v;    // tile col -1: halo, coeff 0
    }
    __syncthreads();
    float cvm1 = (wv == 0) ? 0.0f : cvB[wv - 1][lane];   // cv at tile row r0-1

    for (int it = 0; it < 8; it++) {
        xT[wv][lane] = u[0];
        xB[wv][lane] = u[15];
        __syncthreads();
        float ub = (wv > 0) ? xB[wv - 1][lane] : u[0];
        float ut = (wv < 3) ? xT[wv + 1][lane] : u[15];
        float V[16];
        #pragma unroll
        for (int k = 0; k < 16; k++) {
            float up = (k == 0) ? ub : u[k - 1];
            float dn = (k == 15) ? ut : u[k + 1];
            float cup = (k == 0) ? cvm1 : cvr[k - 1];
            V[k] = u[k] + LDIFF * cvr[k] * (dn - u[k]) - LDIFF * cup * (u[k] - up);
        }
        #pragma unroll
        for (int k = 0; k < 16; k++) {
            float lf = __shfl(V[k], (lane + 63) & 63);
            float rt = __shfl(V[k], (lane + 1) & 63);
            u[k] = V[k] + LDIFF * chr[k] * (rt - V[k]) - LDIFF * chl[k] * (V[k] - lf);
        }
        __syncthreads();
    }

    if (lane >= 8 && lane < 56) {
        int gx = gx0 + lane;
        if (gx < 512) {
            #pragma unroll
            for (int k = 0; k < 16; k++) {
                int r = r0 + k;
                if (r >= 8 && r < 56) {
                    int gy = gy0 + r;
                    if (gy < 512) O[b * HW + gy * W + gx] = u[k];
                }
            }
        }
    }
}

extern "C" void kernel_launch(void* const* d_in, const int* in_sizes, int n_in,
                              void* d_out, int out_size, void* d_ws, size_t ws_size,
                              hipStream_t stream) {
    const float* guide   = (const float*)d_in[0];
    const float* initial = (const float*)d_in[1];
    float* y_pred = (float*)d_out;
    float* cv = y_pred + N_D;          // output 1
    float* ch = cv + N_CV;             // output 2

    uint8_t* w = (uint8_t*)d_ws;
    int* flags = (int*)w;                                // 242 ints
    float* D = (float*)(w + 1024);                       // 2 MB depth
    float* T = (float*)(w + 1024 + (size_t)N_D * 4);     // 2 MB temp

    hipMemsetAsync(flags, 0, NB * 121 * sizeof(int), stream);
    kcvch<<<N_D / 256, 256, 0, stream>>>(guide, initial, cv, ch, D);
    kwave<<<dim3(121, 2), 256, 0, stream>>>(D, cv, ch, flags);

    // 64 diffusion iterations = 8 launches of 8 fused iterations; last writes y_pred
    float* in = D; float* out = T;
    for (int l = 0; l < 8; l++) {
        float* o = (l == 7) ? y_pred : out;
        kdiff8<<<dim3(NBLKS, NBLKS, 2), 256, 0, stream>>>(in, cv, ch, o);
        float* tmp = in; in = out; out = tmp;
    }
}

// Round 4
// 475.969 us; speedup vs baseline: 2.4010x; 1.6248x over previous
//
#include <hip/hip_runtime.h>
#include <stdint.h>

#define LDIFF 0.24f

constexpr int H = 512, W = 512, NB = 2;
constexpr int HW = H * W;              // 262144 = 2^18
constexpr int N_D = NB * HW;           // 524288
constexpr int CVH = 511, CVW = 512;
constexpr int CHH = 512, CHW = 511;
constexpr int N_CV = NB * CVH * CVW;   // 523264
constexpr int NBLKS = 11;              // 11x11 block grid, step 48

// ---------------- cv / ch (written straight into d_out) + depth copy + flag init ----
// NOTE: shift is dropped everywhere: all downstream ops preserve additive
// constants exactly, so y_pred = F(initial+shift)-shift == F(initial).
__global__ void kcvch(const float* __restrict__ guide, const float* __restrict__ initial,
                      float* __restrict__ cv, float* __restrict__ ch, float* __restrict__ D,
                      int* __restrict__ flags) {
    int idx = blockIdx.x * 256 + threadIdx.x;   // < 524288
    if (idx < NB * 121) flags[idx] = 0;         // visible to kwave via dispatch-boundary flush
    int b = idx >> 18;
    int yx = idx & (HW - 1);
    int y = yx >> 9, x = yx & 511;
    const float* g = guide + (size_t)b * 3 * HW + yx;
    const float kinv = 1.0f / (0.03f * 0.03f);
    D[idx] = initial[idx];
    if (y < 511) {
        float d = (fabsf(g[512] - g[0]) + fabsf(g[HW + 512] - g[HW]) + fabsf(g[2 * HW + 512] - g[2 * HW])) * (1.0f / 3.0f);
        cv[b * CVH * CVW + y * CVW + x] = 1.0f / (1.0f + d * d * kinv);
    }
    if (x < 511) {
        float d = (fabsf(g[1] - g[0]) + fabsf(g[HW + 1] - g[HW]) + fabsf(g[2 * HW + 1] - g[2 * HW])) * (1.0f / 3.0f);
        ch[b * CHH * CHW + y * CHW + x] = 1.0f / (1.0f + d * d * kinv);
    }
}

// ---------------- single-launch wavefront: params + periodic stencil + blend ----------------
// Block (b,i,j). Deps: (i,j-1),(i-1,j-1),(i-1,j),(i-1,j+1) via device-scope flags.
// 242 blocks <= 256 CUs -> all co-resident, spin-wait is safe.
// Sync discipline: RELAXED polls (sc1 read-through, no cache-invalidate) +
// single acquire fence after observation; release store publishes writes.
__global__ __launch_bounds__(256) void kwave(float* __restrict__ depth,
                                             const float* __restrict__ cv,
                                             const float* __restrict__ ch,
                                             int* __restrict__ flags) {
    __shared__ float pool[8712];      // aliased: {cvT[4356], chT[4356]} then {A[4096], Bs[4096]}
    __shared__ float sm[256];
    __shared__ float prmS[3];
    __shared__ float xT[4][64];
    __shared__ float xB[4][64];
    float* cvT = pool;
    float* chT = pool + 4356;
    float* A   = pool;
    float* Bs  = pool + 4096;

    int idx = blockIdx.x;            // 0..120
    int i = idx / NBLKS, j = idx % NBLKS;
    int b = blockIdx.y;
    int tid = threadIdx.x;
    int y0 = i * 48, x0 = j * 48;
    int y1 = min(y0 + 64, 512), x1 = min(x0 + 64, 512);
    int bh = y1 - y0, bw = x1 - x0;
    const float* cvb = cv + b * CVH * CVW;
    const float* chb = ch + b * CHH * CHW;

    // ---- stage 66x66 cv/ch tiles (rows y0-1..y0+64, cols x0-1..x0+64; zero at array edges) ----
    for (int p = tid; p < 66 * 66; p += 256) {
        int rr = p / 66, cc = p - rr * 66;
        int y = y0 - 1 + rr, x = x0 - 1 + cc;
        cvT[p] = (y >= 0 && y < 511 && x >= 0 && x < 512) ? cvb[y * CVW + x] : 0.0f;
        chT[p] = (y >= 0 && y < 512 && x >= 0 && x < 511) ? chb[y * CHW + x] : 0.0f;
    }
    __syncthreads();

    // ---- per-block params from LDS ----
    float scv = 0.f, sch = 0.f, sun = 0.f;
    {
        int n = (bh - 1) * bw;
        for (int p = tid; p < n; p += 256) { int r = p / bw, c = p - r * bw; scv += cvT[(r + 1) * 66 + c + 1]; }
    }
    {
        int cols = bw - 1, n = bh * cols;
        for (int p = tid; p < n; p += 256) { int r = p / cols, c = p - r * cols; sch += chT[(r + 1) * 66 + c + 1]; }
    }
    int ur = min(y1, 511) - y0, uc = min(x1, 511) - x0;
    {
        int n = ur * uc;
        for (int p = tid; p < n; p += 256) {
            int r = p / uc, c = p - r * uc;
            float s1 = 0.f, s2 = 0.f, t1 = 0.f, t2 = 0.f;
            #pragma unroll
            for (int dy = 0; dy < 3; dy++)
                #pragma unroll
                for (int dx = 0; dx < 3; dx++) {
                    float v = cvT[(r + dy) * 66 + c + dx]; s1 += v; s2 += v * v;
                    float w2 = chT[(r + dy) * 66 + c + dx]; t1 += w2; t2 += w2 * w2;
                }
            float m = s1 * (1.0f / 9.0f);
            float vcv = s2 * (1.0f / 9.0f) - m * m;
            m = t1 * (1.0f / 9.0f);
            float vch = t2 * (1.0f / 9.0f) - m * m;
            if (vcv < 0.1f && vch < 0.1f) sun += 1.f;
        }
    }
    sm[tid] = scv; __syncthreads();
    for (int s = 128; s; s >>= 1) { if (tid < s) sm[tid] += sm[tid + s]; __syncthreads(); }
    if (tid == 0) prmS[0] = sm[0] / (float)((bh - 1) * bw);
    __syncthreads();
    sm[tid] = sch; __syncthreads();
    for (int s = 128; s; s >>= 1) { if (tid < s) sm[tid] += sm[tid + s]; __syncthreads(); }
    if (tid == 0) prmS[1] = sm[0] / (float)(bh * (bw - 1));
    __syncthreads();
    sm[tid] = sun; __syncthreads();
    for (int s = 128; s; s >>= 1) { if (tid < s) sm[tid] += sm[tid + s]; __syncthreads(); }
    if (tid == 0) prmS[2] = (sm[0] / (float)(ur * uc) > 0.7f) ? 1.0f : 0.0f;
    __syncthreads();

    int me = b * 121 + idx;
    if (prmS[2] <= 0.5f) {
        // no write -> signal immediately (successors wait their own other deps)
        if (tid == 0) __hip_atomic_store(&flags[me], 1, __ATOMIC_RELEASE, __HIP_MEMORY_SCOPE_AGENT);
        return;
    }

    // ---- wait dependencies: relaxed polls, acquire once ----
    if (tid < 4) {
        int di = (tid == 0) ? i : i - 1;
        int dj = (tid == 0) ? j - 1 : j - 2 + tid;   // tid1->j-1, tid2->j, tid3->j+1
        if (di >= 0 && dj >= 0 && dj < NBLKS) {
            int d = b * 121 + di * NBLKS + dj;
            int spins = 0;
            while (__hip_atomic_load(&flags[d], __ATOMIC_RELAXED, __HIP_MEMORY_SCOPE_AGENT) == 0) {
                __builtin_amdgcn_s_sleep(1);
                if (((++spins) & 2047) == 0)
                    __builtin_amdgcn_fence(__ATOMIC_ACQUIRE, "agent");  // forward-progress hedge
            }
        }
    }
    __syncthreads();
    __builtin_amdgcn_fence(__ATOMIC_ACQUIRE, "agent");   // make predecessors' depth writes visible

    float a = LDIFF * prmS[0], bc = LDIFF * prmS[1];
    float* base = depth + b * HW;
    int lane = tid & 63, wv = tid >> 6, r0 = wv * 16;

    if (bh == 64 && bw == 64) {
        // ---- fast path: registers + shfl, periodic 64x64 ----
        float u[16], orig[16];
        #pragma unroll
        for (int k = 0; k < 16; k++) { orig[k] = base[(y0 + r0 + k) * W + x0 + lane]; u[k] = orig[k]; }
        for (int it = 0; it < 10; it++) {
            xT[wv][lane] = u[0];
            xB[wv][lane] = u[15];
            __syncthreads();
            float ub = xB[(wv + 3) & 3][lane];   // row r0-1 (periodic)
            float ut = xT[(wv + 1) & 3][lane];   // row r0+16 (periodic)
            float nu[16];
            #pragma unroll
            for (int k = 0; k < 16; k++) {
                float up = (k == 0) ? ub : u[k - 1];
                float dn = (k == 15) ? ut : u[k + 1];
                float lf = __shfl(u[k], (lane + 63) & 63);
                float rt = __shfl(u[k], (lane + 1) & 63);
                nu[k] = u[k] + a * (up + dn - 2.0f * u[k]) + bc * (lf + rt - 2.0f * u[k]);
            }
            #pragma unroll
            for (int k = 0; k < 16; k++) u[k] = nu[k];
            __syncthreads();
        }
        float bxw = (x0 > 0 && lane < 16) ? (float)lane * (1.0f / 16.0f) : 1.0f;
        #pragma unroll
        for (int k = 0; k < 16; k++) {
            int r = r0 + k;
            float byw = (y0 > 0 && r < 16) ? (float)r * (1.0f / 16.0f) : 1.0f;
            float wgt = byw * bxw;
            base[(y0 + r) * W + x0 + lane] = orig[k] * (1.0f - wgt) + u[k] * wgt;
        }
    } else {
        // ---- LDS fallback for 32-sized edge blocks ----
        int lw = (bw == 64) ? 6 : 5;
        int mw = bw - 1, mh = bh - 1;
        int n = bh * bw;
        for (int p = tid; p < n; p += 256) {
            int r = p >> lw, c = p & mw;
            A[p] = base[(y0 + r) * W + x0 + c];
        }
        __syncthreads();
        float* src = A; float* dst = Bs;
        for (int s = 0; s < 10; s++) {
            for (int p = tid; p < n; p += 256) {
                int r = p >> lw, c = p & mw;
                float u = src[p];
                float up = src[(((r - 1) & mh) << lw) + c];
                float dn = src[(((r + 1) & mh) << lw) + c];
                float lf = src[(r << lw) + ((c - 1) & mw)];
                float rt = src[(r << lw) + ((c + 1) & mw)];
                dst[p] = u + a * (up + dn - 2.0f * u) + bc * (lf + rt - 2.0f * u);
            }
            __syncthreads();
            float* tmp = src; src = dst; dst = tmp;
        }
        for (int p = tid; p < n; p += 256) {
            int r = p >> lw, c = p & mw;
            float by = (y0 > 0 && r < 16) ? (float)r * (1.0f / 16.0f) : 1.0f;
            float bx = (x0 > 0 && c < 16) ? (float)c * (1.0f / 16.0f) : 1.0f;
            float wgt = by * bx;
            int g = (y0 + r) * W + x0 + c;
            float orig = base[g];
            base[g] = orig * (1.0f - wgt) + src[p] * wgt;
        }
    }
    __syncthreads();   // all depth stores drained to L2 before publish
    if (tid == 0) __hip_atomic_store(&flags[me], 1, __ATOMIC_RELEASE, __HIP_MEMORY_SCOPE_AGENT);
}

// ---------------- fused 8-iteration diffusion, registers + shfl ----------------
// Tile 64x64 (output 48x48, halo 8). Wave wv owns rows [16wv,16wv+16), col = lane.
// cv/ch zero outside valid ranges == exact boundary handling.
__global__ __launch_bounds__(256) void kdiff8(const float* __restrict__ I,
                                              const float* __restrict__ cv,
                                              const float* __restrict__ ch,
                                              float* __restrict__ O) {
    __shared__ float xT[4][64];
    __shared__ float xB[4][64];
    __shared__ float cvB[4][64];
    int bx = blockIdx.x, by = blockIdx.y, b = blockIdx.z;
    int gy0 = by * 48 - 8, gx0 = bx * 48 - 8;
    int tid = threadIdx.x;
    int lane = tid & 63, wv = tid >> 6, r0 = wv * 16;
    const float* Ib = I + b * HW;
    const float* cvb = cv + b * CVH * CVW;
    const float* chb = ch + b * CHH * CHW;
    int cx = gx0 + lane;
    int gxc = min(max(cx, 0), 511);
    bool xvalid = (cx >= 0 && cx < 512);

    float u[16], cvr[16], chr[16], chl[16];
    #pragma unroll
    for (int k = 0; k < 16; k++) {
        int cy = gy0 + r0 + k;
        int gyc = min(max(cy, 0), 511);
        u[k] = Ib[gyc * W + gxc];
        cvr[k] = (cy >= 0 && cy < 511 && xvalid) ? cvb[cy * CVW + cx] : 0.0f;
        chr[k] = (cy >= 0 && cy < 512 && xvalid && cx < 511) ? chb[cy * CHW + cx] : 0.0f;
    }
    cvB[wv][lane] = cvr[15];
    #pragma unroll
    for (int k = 0; k < 16; k++) {
        float v = __shfl(chr[k], (lane + 63) & 63);
        chl[k] = (lane == 0) ? 0.0f : v;    // tile col -1: halo, coeff 0
    }
    __syncthreads();
    float cvm1 = (wv == 0) ? 0.0f : cvB[wv - 1][lane];   // cv at tile row r0-1

    for (int it = 0; it < 8; it++) {
        xT[wv][lane] = u[0];
        xB[wv][lane] = u[15];
        __syncthreads();
        float ub = (wv > 0) ? xB[wv - 1][lane] : u[0];
        float ut = (wv < 3) ? xT[wv + 1][lane] : u[15];
        float V[16];
        #pragma unroll
        for (int k = 0; k < 16; k++) {
            float up = (k == 0) ? ub : u[k - 1];
            float dn = (k == 15) ? ut : u[k + 1];
            float cup = (k == 0) ? cvm1 : cvr[k - 1];
            V[k] = u[k] + LDIFF * cvr[k] * (dn - u[k]) - LDIFF * cup * (u[k] - up);
        }
        #pragma unroll
        for (int k = 0; k < 16; k++) {
            float lf = __shfl(V[k], (lane + 63) & 63);
            float rt = __shfl(V[k], (lane + 1) & 63);
            u[k] = V[k] + LDIFF * chr[k] * (rt - V[k]) - LDIFF * chl[k] * (V[k] - lf);
        }
        __syncthreads();
    }

    if (lane >= 8 && lane < 56) {
        int gx = gx0 + lane;
        if (gx < 512) {
            #pragma unroll
            for (int k = 0; k < 16; k++) {
                int r = r0 + k;
                if (r >= 8 && r < 56) {
                    int gy = gy0 + r;
                    if (gy < 512) O[b * HW + gy * W + gx] = u[k];
                }
            }
        }
    }
}

extern "C" void kernel_launch(void* const* d_in, const int* in_sizes, int n_in,
                              void* d_out, int out_size, void* d_ws, size_t ws_size,
                              hipStream_t stream) {
    const float* guide   = (const float*)d_in[0];
    const float* initial = (const float*)d_in[1];
    float* y_pred = (float*)d_out;
    float* cv = y_pred + N_D;          // output 1
    float* ch = cv + N_CV;             // output 2

    uint8_t* w = (uint8_t*)d_ws;
    int* flags = (int*)w;                                // 242 ints
    float* D = (float*)(w + 1024);                       // 2 MB depth
    float* T = (float*)(w + 1024 + (size_t)N_D * 4);     // 2 MB temp

    kcvch<<<N_D / 256, 256, 0, stream>>>(guide, initial, cv, ch, D, flags);
    kwave<<<dim3(121, 2), 256, 0, stream>>>(D, cv, ch, flags);

    // 64 diffusion iterations = 8 launches of 8 fused iterations; last writes y_pred
    float* in = D; float* out = T;
    for (int l = 0; l < 8; l++) {
        float* o = (l == 7) ? y_pred : out;
        kdiff8<<<dim3(NBLKS, NBLKS, 2), 256, 0, stream>>>(in, cv, ch, o);
        float* tmp = in; in = out; out = tmp;
    }
}